// Round 7
// baseline (362.586 us; speedup 1.0000x reference)
//
#include <hip/hip_runtime.h>
#include <hip/hip_bf16.h>

// GraphSAGE 2-layer forward, bf16 datapath + cache-line-aware CSR build.
// agg: 8 lanes/node (32B/lane), unroll-4 -> 8KB outstanding/wave (MLP probe).
// CSR: 512-node buckets (196 blocks), LDS multisplit bin, wave-shfl scan.
// GEMM: mfma 16x16x32, 2Mx2N wave tiling (1 B-read : 4 MFMA), W LDS-swizzled.
// xcat/hcat: [n_pad][256] bf16 rows = [feat(128) | agg(128)]; Wcat[N][256] bf16 B^T.

#define D_FEAT 128
#define BSHIFT 9
#define BUCKET 512
#define MAXNB 256   // max buckets (n <= 131072), bucket = 512 nodes
#define CAP 24      // LDS stash per bucket per block-batch (mean ~10.4)

typedef __attribute__((ext_vector_type(8))) short bf16x8;
typedef __attribute__((ext_vector_type(4))) float f32x4;

__device__ __forceinline__ ushort f2bf(float f) {
    __hip_bfloat16 h = __float2bfloat16(f);
    return *(ushort*)&h;
}
__device__ __forceinline__ uint pack2(float lo, float hi) {
    return (uint)f2bf(lo) | ((uint)f2bf(hi) << 16);
}
__device__ __forceinline__ void acc8(float* a, uint4 v) {
    a[0] += __uint_as_float(v.x << 16);
    a[1] += __uint_as_float(v.x & 0xffff0000u);
    a[2] += __uint_as_float(v.y << 16);
    a[3] += __uint_as_float(v.y & 0xffff0000u);
    a[4] += __uint_as_float(v.z << 16);
    a[5] += __uint_as_float(v.z & 0xffff0000u);
    a[6] += __uint_as_float(v.w << 16);
    a[7] += __uint_as_float(v.w & 0xffff0000u);
}

// ---------------- bucket histogram (nb <= 256, 256 threads cover all) ----------------
__global__ __launch_bounds__(256) void bucket_hist(const int* __restrict__ dst, int* __restrict__ bucket_cnt,
                                                   int e, int nb) {
    __shared__ int h[MAXNB];
    int tid = threadIdx.x;
    h[tid] = 0;
    __syncthreads();
    int i0 = blockIdx.x * 2048 + tid * 8;
    if (i0 + 8 <= e) {
        int4 a = *(const int4*)(dst + i0);
        int4 b = *(const int4*)(dst + i0 + 4);
        atomicAdd(&h[a.x >> BSHIFT], 1);
        atomicAdd(&h[a.y >> BSHIFT], 1);
        atomicAdd(&h[a.z >> BSHIFT], 1);
        atomicAdd(&h[a.w >> BSHIFT], 1);
        atomicAdd(&h[b.x >> BSHIFT], 1);
        atomicAdd(&h[b.y >> BSHIFT], 1);
        atomicAdd(&h[b.z >> BSHIFT], 1);
        atomicAdd(&h[b.w >> BSHIFT], 1);
    } else {
        for (int k = 0; k < 8; ++k)
            if (i0 + k < e) atomicAdd(&h[dst[i0 + k] >> BSHIFT], 1);
    }
    __syncthreads();
    if (tid < nb && h[tid]) atomicAdd(&bucket_cnt[tid], h[tid]);
}

// ---------------- bucket scan (nb <= 256) ----------------
__global__ __launch_bounds__(256) void bucket_scan(const int* __restrict__ bucket_cnt, int* __restrict__ bucket_base,
                                                   int* __restrict__ gcur, int* __restrict__ row_start,
                                                   int nb, int n, int e) {
    __shared__ int sm[256];
    int tid = threadIdx.x;
    int v = (tid < nb) ? bucket_cnt[tid] : 0;
    sm[tid] = v;
    __syncthreads();
    for (int off = 1; off < 256; off <<= 1) {
        int t = (tid >= off) ? sm[tid - off] : 0;
        __syncthreads();
        sm[tid] += t;
        __syncthreads();
    }
    if (tid < nb) {
        int excl = sm[tid] - v;
        bucket_base[tid] = excl;
        gcur[tid] = excl;
    }
    if (tid == nb) bucket_base[tid] = e;  // nb < 256 here
    if (tid == 0) row_start[n] = e;
}

// ---------------- bin edges: LDS multisplit (MAXNB=256 == blockDim) ----------------
__global__ __launch_bounds__(256) void bin_edges(const int* __restrict__ src, const int* __restrict__ dst,
                                                 int* __restrict__ gcur, uint2* __restrict__ temp, int e) {
    __shared__ uint2 buf[MAXNB][CAP];
    __shared__ int cnt[MAXNB], c[MAXNB], sc[MAXNB], gb[MAXNB];
    __shared__ int pre[MAXNB + 1];

    int tid = threadIdx.x;
    cnt[tid] = 0;
    __syncthreads();

    int i0 = blockIdx.x * 2048 + tid * 8;
    if (i0 + 8 <= e) {
        int4 s0 = *(const int4*)(src + i0);
        int4 s1 = *(const int4*)(src + i0 + 4);
        int4 d0 = *(const int4*)(dst + i0);
        int4 d1 = *(const int4*)(dst + i0 + 4);
        int ss[8] = {s0.x, s0.y, s0.z, s0.w, s1.x, s1.y, s1.z, s1.w};
        int dd[8] = {d0.x, d0.y, d0.z, d0.w, d1.x, d1.y, d1.z, d1.w};
#pragma unroll
        for (int k = 0; k < 8; ++k) {
            int b = dd[k] >> BSHIFT;
            uint2 pr = make_uint2((uint)ss[k], (uint)dd[k]);
            int p = atomicAdd(&cnt[b], 1);
            if (p < CAP) buf[b][p] = pr;
            else temp[atomicAdd(&gcur[b], 1)] = pr;
        }
    } else {
        for (int k = 0; k < 8; ++k) {
            if (i0 + k < e) {
                int b = dst[i0 + k] >> BSHIFT;
                uint2 pr = make_uint2((uint)src[i0 + k], (uint)dst[i0 + k]);
                int p = atomicAdd(&cnt[b], 1);
                if (p < CAP) buf[b][p] = pr;
                else temp[atomicAdd(&gcur[b], 1)] = pr;
            }
        }
    }
    __syncthreads();

    // prefix over stashed counts
    c[tid] = min(cnt[tid], CAP);
    sc[tid] = c[tid];
    __syncthreads();
    for (int off = 1; off < 256; off <<= 1) {
        int t = (tid >= off) ? sc[tid - off] : 0;
        __syncthreads();
        sc[tid] += t;
        __syncthreads();
    }
    pre[tid] = sc[tid] - c[tid];
    gb[tid] = (c[tid] > 0) ? atomicAdd(&gcur[tid], c[tid]) : 0;
    if (tid == 0) pre[MAXNB] = sc[MAXNB - 1];
    __syncthreads();

    int S = pre[MAXNB];
    for (int idx = tid; idx < S; idx += 256) {
        int lo = 0, hi = MAXNB;
        while (hi - lo > 1) {
            int mid = (lo + hi) >> 1;
            if (pre[mid] <= idx) lo = mid;
            else hi = mid;
        }
        int ofs = idx - pre[lo];
        temp[gb[lo] + ofs] = buf[lo][ofs];
    }
}

// ---------------- build bucket: 512 nodes/block, wave-shfl scan ----------------
__global__ __launch_bounds__(512) void build_bucket(const uint2* __restrict__ temp,
                                                    const int* __restrict__ bucket_base,
                                                    int* __restrict__ row_start, float* __restrict__ inv_deg,
                                                    int* __restrict__ csr_src, int n) {
    __shared__ int deg[BUCKET], cur[BUCKET], rs[BUCKET], wsum[8];
    int tid = threadIdx.x;
    int b = blockIdx.x;
    int base = bucket_base[b];
    int ecnt = bucket_base[b + 1] - base;
    int node0 = b << BSHIFT;
    int ncnt = min(BUCKET, n - node0);

    deg[tid] = 0;
    __syncthreads();
    for (int i = tid; i < ecnt; i += BUCKET) {
        int d = (int)temp[base + i].y - node0;
        atomicAdd(&deg[d], 1);
    }
    __syncthreads();

    int d = deg[tid];
    int v = d;
#pragma unroll
    for (int off = 1; off < 64; off <<= 1) {
        int t = __shfl_up(v, off);
        if ((tid & 63) >= off) v += t;
    }
    int wv = tid >> 6;  // 0..7
    if ((tid & 63) == 63) wsum[wv] = v;
    __syncthreads();
    if (tid < 8) {
        int w = wsum[tid];
#pragma unroll
        for (int off = 1; off < 8; off <<= 1) {
            int t = __shfl_up(w, off);
            if (tid >= off) w += t;
        }
        wsum[tid] = w;
    }
    __syncthreads();
    int excl = v + (wv ? wsum[wv - 1] : 0) - d;

    if (tid < ncnt) {
        row_start[node0 + tid] = base + excl;
        inv_deg[node0 + tid] = d ? 1.0f / (float)d : 0.0f;
    }
    rs[tid] = excl;
    cur[tid] = 0;
    __syncthreads();
    for (int i = tid; i < ecnt; i += BUCKET) {
        uint2 p = temp[base + i];
        int l = (int)p.y - node0;
        int pos = atomicAdd(&cur[l], 1);
        csr_src[base + rs[l] + pos] = (int)p.x;
    }
}

// ---------------- fused convert: x -> xcat[:,0:128], weights -> w1cat/w2cat ----------------
__global__ __launch_bounds__(256) void convert_all(const float* __restrict__ x, ushort* __restrict__ xcat,
                                                   const float* __restrict__ W1s, const float* __restrict__ W1n,
                                                   const float* __restrict__ W2s, const float* __restrict__ W2n,
                                                   ushort* __restrict__ w1cat, ushort* __restrict__ w2cat,
                                                   int total8) {
    int i = blockIdx.x * 256 + threadIdx.x;
    if (i < total8) {
        int e = i * 8;
        int row = e >> 7, col = e & 127;
        float4 v0 = *(const float4*)(x + e);
        float4 v1 = *(const float4*)(x + e + 4);
        uint4 o;
        o.x = pack2(v0.x, v0.y);
        o.y = pack2(v0.z, v0.w);
        o.z = pack2(v1.x, v1.y);
        o.w = pack2(v1.z, v1.w);
        *(uint4*)(xcat + (size_t)row * 256 + col) = o;
    } else {
        int idx = i - total8;
        if (idx < 128 * 256) {
            int c = idx >> 8, k = idx & 255;
            float v = (k < 128) ? W1s[k * 128 + c] : W1n[(k - 128) * 128 + c];
            w1cat[idx] = f2bf(v);
        } else if (idx < 128 * 256 + 64 * 256) {
            int j = idx - 128 * 256;
            int c = j >> 8, k = j & 255;
            float v = (k < 128) ? W2s[k * 64 + c] : W2n[(k - 128) * 64 + c];
            w2cat[j] = f2bf(v);
        }
    }
}

// ---------------- aggregation: 8 lanes/node (32B/lane), unroll-4 ----------------
__global__ __launch_bounds__(256) void aggregate_bf16(const ushort* __restrict__ featbase,
                                                      const int* __restrict__ row_start,
                                                      const int* __restrict__ csr_src,
                                                      const float* __restrict__ inv_deg,
                                                      ushort* __restrict__ outbase, int n) {
    int g = (blockIdx.x * 256 + threadIdx.x) >> 3;
    int ngroups = gridDim.x * 32;
    int gl = threadIdx.x & 7;
    const uint4* fb = (const uint4*)featbase;  // 32 uint4 per 512B row; feat half = first 16

    for (int node = g; node < n; node += ngroups) {
        int beg = row_start[node];
        int end = row_start[node + 1];

        float a[16];
#pragma unroll
        for (int j = 0; j < 16; ++j) a[j] = 0.f;

        int ei = beg;
        for (; ei + 4 <= end; ei += 4) {
            int s0 = csr_src[ei];
            int s1 = csr_src[ei + 1];
            int s2 = csr_src[ei + 2];
            int s3 = csr_src[ei + 3];
            uint4 u0 = fb[(size_t)s0 * 32 + gl * 2];
            uint4 w0 = fb[(size_t)s0 * 32 + gl * 2 + 1];
            uint4 u1 = fb[(size_t)s1 * 32 + gl * 2];
            uint4 w1 = fb[(size_t)s1 * 32 + gl * 2 + 1];
            uint4 u2 = fb[(size_t)s2 * 32 + gl * 2];
            uint4 w2 = fb[(size_t)s2 * 32 + gl * 2 + 1];
            uint4 u3 = fb[(size_t)s3 * 32 + gl * 2];
            uint4 w3 = fb[(size_t)s3 * 32 + gl * 2 + 1];
            acc8(a, u0); acc8(a + 8, w0);
            acc8(a, u1); acc8(a + 8, w1);
            acc8(a, u2); acc8(a + 8, w2);
            acc8(a, u3); acc8(a + 8, w3);
        }
        for (; ei < end; ++ei) {
            int s = csr_src[ei];
            uint4 u = fb[(size_t)s * 32 + gl * 2];
            uint4 w = fb[(size_t)s * 32 + gl * 2 + 1];
            acc8(a, u); acc8(a + 8, w);
        }

        float w = inv_deg[node];
        uint4 o0, o1;
        o0.x = pack2(a[0] * w, a[1] * w);
        o0.y = pack2(a[2] * w, a[3] * w);
        o0.z = pack2(a[4] * w, a[5] * w);
        o0.w = pack2(a[6] * w, a[7] * w);
        o1.x = pack2(a[8] * w, a[9] * w);
        o1.y = pack2(a[10] * w, a[11] * w);
        o1.z = pack2(a[12] * w, a[13] * w);
        o1.w = pack2(a[14] * w, a[15] * w);
        uint4* op = (uint4*)(outbase + (size_t)node * 256 + gl * 16);
        op[0] = o0;
        op[1] = o1;
    }
}

// ---------------- MFMA GEMM: Y[n][NCOL] = A[n_pad][256] @ Wcat^T + bias ----------------
// 4 waves = 2(M) x 2(N); wave owns 64 rows x NCOL/2 cols -> 1 B-read : 4 MFMA.
template <int NTT, bool RELU, bool OUTBF16>
__global__ __launch_bounds__(256) void gemm_mfma(const ushort* __restrict__ A, const ushort* __restrict__ Wcat,
                                                 const float* __restrict__ bias, ushort* __restrict__ Yb,
                                                 float* __restrict__ Yf, int n) {
    constexpr int NCOL = NTT * 16;
    constexpr int NT = NTT / 2;  // n-tiles per wave
    __shared__ ushort Wlds[NCOL * 128];  // one 128-K chunk, XOR-swizzled rows of 256B

    int tid = threadIdx.x;
    int wave = tid >> 6, lane = tid & 63;
    int wm = wave >> 1, wn = wave & 1;
    int lrow = lane & 15, lk = lane >> 4;
    int m0 = blockIdx.x * 128 + wm * 64;

    f32x4 acc[4][NT];
#pragma unroll
    for (int mi = 0; mi < 4; ++mi)
#pragma unroll
        for (int nj = 0; nj < NT; ++nj) acc[mi][nj] = (f32x4)0.f;

    for (int chunk = 0; chunk < 2; ++chunk) {
        // stage W chunk
        for (int f = tid; f < NCOL * 16; f += 256) {
            int c = f >> 4;
            int kk = (f & 15) * 8;
            uint4 w = *(const uint4*)(Wcat + c * 256 + chunk * 128 + kk);
            uint baddr = ((uint)(c * 256 + kk * 2)) ^ ((uint)(c & 7) << 4);
            *(uint4*)((char*)Wlds + baddr) = w;
        }
        // A fragments for this chunk (issue before barrier; overlaps staging drain)
        bf16x8 af[4][4];
#pragma unroll
        for (int mi = 0; mi < 4; ++mi) {
            const ushort* Ar = A + (size_t)(m0 + mi * 16 + lrow) * 256 + chunk * 128 + lk * 8;
#pragma unroll
            for (int ks = 0; ks < 4; ++ks) af[mi][ks] = *(const bf16x8*)(Ar + ks * 32);
        }
        __syncthreads();

#pragma unroll
        for (int ks = 0; ks < 4; ++ks) {
#pragma unroll
            for (int nj = 0; nj < NT; ++nj) {
                int c = (wn * NT + nj) * 16 + lrow;
                uint baddr = ((uint)(c * 256 + (ks * 32 + lk * 8) * 2)) ^ ((uint)(c & 7) << 4);
                bf16x8 b = *(const bf16x8*)((const char*)Wlds + baddr);
#pragma unroll
                for (int mi = 0; mi < 4; ++mi)
                    acc[mi][nj] = __builtin_amdgcn_mfma_f32_16x16x32_bf16(af[mi][ks], b, acc[mi][nj], 0, 0, 0);
            }
        }
        __syncthreads();
    }

    // epilogue: C/D layout col=lane&15, row=(lane>>4)*4+r  [m89]
#pragma unroll
    for (int nj = 0; nj < NT; ++nj) {
        int col = (wn * NT + nj) * 16 + lrow;
        float bv = bias[col];
#pragma unroll
        for (int mi = 0; mi < 4; ++mi) {
#pragma unroll
            for (int r = 0; r < 4; ++r) {
                int row = m0 + mi * 16 + lk * 4 + r;
                if (row >= n) continue;
                float v = acc[mi][nj][r] + bv;
                if (RELU) v = fmaxf(v, 0.f);
                if (OUTBF16)
                    Yb[(size_t)row * 256 + col] = f2bf(v);
                else
                    Yf[(size_t)row * 64 + col] = v;
            }
        }
    }
}

extern "C" void kernel_launch(void* const* d_in, const int* in_sizes, int n_in,
                              void* d_out, int out_size, void* d_ws, size_t ws_size,
                              hipStream_t stream) {
    const float* x   = (const float*)d_in[0];
    const int*   src = (const int*)d_in[1];
    const int*   dst = (const int*)d_in[2];
    const float* W1s = (const float*)d_in[3];
    const float* W1n = (const float*)d_in[4];
    const float* b1  = (const float*)d_in[5];
    const float* W2s = (const float*)d_in[6];
    const float* W2n = (const float*)d_in[7];
    const float* b2  = (const float*)d_in[8];
    float* out = (float*)d_out;

    const int n = in_sizes[0] / D_FEAT;       // 100000
    const int e = in_sizes[1];                // 1600000
    const int nb = (n + BUCKET - 1) >> BSHIFT;  // 196
    const int n_pad = (n + 127) & ~127;       // 128-row multiple for GEMM

    // ---- workspace carve ----
    char* ws = (char*)d_ws;
    auto take = [&](size_t bytes) {
        void* p = (void*)ws;
        ws += (bytes + 255) & ~(size_t)255;
        return p;
    };
    int*    bucket_cnt  = (int*)take((size_t)MAXNB * 4);
    int*    bucket_base = (int*)take((size_t)(MAXNB + 1) * 4);
    int*    gcur        = (int*)take((size_t)MAXNB * 4);
    int*    row_start   = (int*)take((size_t)(n + 1) * 4);
    float*  inv_deg     = (float*)take((size_t)n * 4);
    int*    csr_src     = (int*)take((size_t)e * 4);
    ushort* xcat        = (ushort*)take((size_t)n_pad * 256 * 2);
    ushort* hcat        = (ushort*)take((size_t)n_pad * 256 * 2);
    ushort* w1cat       = (ushort*)take((size_t)128 * 256 * 2);
    ushort* w2cat       = (ushort*)take((size_t)64 * 256 * 2);
    uint2*  temp        = (uint2*)hcat;  // alias: dead until gemm1 writes hcat

    hipMemsetAsync(bucket_cnt, 0, MAXNB * 4, stream);

    const int ebk = (e + 2047) / 2048;
    bucket_hist<<<ebk, 256, 0, stream>>>(dst, bucket_cnt, e, nb);

    const int total8 = n * 16;
    const int cvt_items = total8 + 128 * 256 + 64 * 256;
    convert_all<<<(cvt_items + 255) / 256, 256, 0, stream>>>(x, xcat, W1s, W1n, W2s, W2n, w1cat, w2cat, total8);

    bucket_scan<<<1, 256, 0, stream>>>(bucket_cnt, bucket_base, gcur, row_start, nb, n, e);
    bin_edges<<<ebk, 256, 0, stream>>>(src, dst, gcur, temp, e);
    build_bucket<<<nb, BUCKET, 0, stream>>>(temp, bucket_base, row_start, inv_deg, csr_src, n);

    const int agg_blocks = 3125;  // 100000 groups of 8 lanes -> 1 node/group

    // layer 1: agg(x) -> xcat[:,128:], then h = relu([x|agg] @ W1cat^T + b1) -> hcat[:,0:128]
    aggregate_bf16<<<agg_blocks, 256, 0, stream>>>(xcat, row_start, csr_src, inv_deg, xcat + 128, n);
    gemm_mfma<8, true, true><<<n_pad / 128, 256, 0, stream>>>(xcat, w1cat, b1, hcat, nullptr, n);

    // layer 2: agg(h) -> hcat[:,128:], then out = [h|agg] @ W2cat^T + b2
    aggregate_bf16<<<agg_blocks, 256, 0, stream>>>(hcat, row_start, csr_src, inv_deg, hcat + 128, n);
    gemm_mfma<4, false, false><<<n_pad / 128, 256, 0, stream>>>(hcat, w2cat, b2, nullptr, out, n);
}

// Round 8
// 330.945 us; speedup vs baseline: 1.0956x; 1.0956x over previous
//
#include <hip/hip_runtime.h>
#include <hip/hip_bf16.h>

// GraphSAGE 2-layer forward. Aggregate-AFTER-projection (linearity):
//   Pn = x@W1n (bf16), Ps = x@W1s (f32);  h = relu(Ps + mean_nbr(Pn) + b1)
//   Tn = h@W2n (bf16), Ts = h@W2s (f32); out = Ts + mean_nbr(Tn) + b2
// Layer-2 gather is 128B/edge (half of before). CSR: 512-node buckets,
// LDS multisplit bin, wave-shfl scan. GEMM: mfma 16x16x32, 2Mx2N wave tiles.

#define D_FEAT 128
#define BSHIFT 9
#define BUCKET 512
#define MAXNB 256   // max buckets (n <= 131072), bucket = 512 nodes
#define CAP 24      // LDS stash per bucket per block-batch (mean ~10.4)

typedef __attribute__((ext_vector_type(8))) short bf16x8;
typedef __attribute__((ext_vector_type(4))) float f32x4;

__device__ __forceinline__ ushort f2bf(float f) {
    __hip_bfloat16 h = __float2bfloat16(f);
    return *(ushort*)&h;
}
__device__ __forceinline__ uint pack2(float lo, float hi) {
    return (uint)f2bf(lo) | ((uint)f2bf(hi) << 16);
}
__device__ __forceinline__ void acc8(float* a, uint4 v) {
    a[0] += __uint_as_float(v.x << 16);
    a[1] += __uint_as_float(v.x & 0xffff0000u);
    a[2] += __uint_as_float(v.y << 16);
    a[3] += __uint_as_float(v.y & 0xffff0000u);
    a[4] += __uint_as_float(v.z << 16);
    a[5] += __uint_as_float(v.z & 0xffff0000u);
    a[6] += __uint_as_float(v.w << 16);
    a[7] += __uint_as_float(v.w & 0xffff0000u);
}

// ---------------- bucket histogram ----------------
__global__ __launch_bounds__(256) void bucket_hist(const int* __restrict__ dst, int* __restrict__ bucket_cnt,
                                                   int e, int nb) {
    __shared__ int h[MAXNB];
    int tid = threadIdx.x;
    h[tid] = 0;
    __syncthreads();
    int i0 = blockIdx.x * 2048 + tid * 8;
    if (i0 + 8 <= e) {
        int4 a = *(const int4*)(dst + i0);
        int4 b = *(const int4*)(dst + i0 + 4);
        atomicAdd(&h[a.x >> BSHIFT], 1);
        atomicAdd(&h[a.y >> BSHIFT], 1);
        atomicAdd(&h[a.z >> BSHIFT], 1);
        atomicAdd(&h[a.w >> BSHIFT], 1);
        atomicAdd(&h[b.x >> BSHIFT], 1);
        atomicAdd(&h[b.y >> BSHIFT], 1);
        atomicAdd(&h[b.z >> BSHIFT], 1);
        atomicAdd(&h[b.w >> BSHIFT], 1);
    } else {
        for (int k = 0; k < 8; ++k)
            if (i0 + k < e) atomicAdd(&h[dst[i0 + k] >> BSHIFT], 1);
    }
    __syncthreads();
    if (tid < nb && h[tid]) atomicAdd(&bucket_cnt[tid], h[tid]);
}

// ---------------- bucket scan (nb <= 256) ----------------
__global__ __launch_bounds__(256) void bucket_scan(const int* __restrict__ bucket_cnt, int* __restrict__ bucket_base,
                                                   int* __restrict__ gcur, int* __restrict__ row_start,
                                                   int nb, int n, int e) {
    __shared__ int sm[256];
    int tid = threadIdx.x;
    int v = (tid < nb) ? bucket_cnt[tid] : 0;
    sm[tid] = v;
    __syncthreads();
    for (int off = 1; off < 256; off <<= 1) {
        int t = (tid >= off) ? sm[tid - off] : 0;
        __syncthreads();
        sm[tid] += t;
        __syncthreads();
    }
    if (tid < nb) {
        int excl = sm[tid] - v;
        bucket_base[tid] = excl;
        gcur[tid] = excl;
    }
    if (tid == nb) bucket_base[tid] = e;  // nb < 256 here
    if (tid == 0) row_start[n] = e;
}

// ---------------- bin edges: LDS multisplit ----------------
__global__ __launch_bounds__(256) void bin_edges(const int* __restrict__ src, const int* __restrict__ dst,
                                                 int* __restrict__ gcur, uint2* __restrict__ temp, int e) {
    __shared__ uint2 buf[MAXNB][CAP];
    __shared__ int cnt[MAXNB], c[MAXNB], sc[MAXNB], gb[MAXNB];
    __shared__ int pre[MAXNB + 1];

    int tid = threadIdx.x;
    cnt[tid] = 0;
    __syncthreads();

    int i0 = blockIdx.x * 2048 + tid * 8;
    if (i0 + 8 <= e) {
        int4 s0 = *(const int4*)(src + i0);
        int4 s1 = *(const int4*)(src + i0 + 4);
        int4 d0 = *(const int4*)(dst + i0);
        int4 d1 = *(const int4*)(dst + i0 + 4);
        int ss[8] = {s0.x, s0.y, s0.z, s0.w, s1.x, s1.y, s1.z, s1.w};
        int dd[8] = {d0.x, d0.y, d0.z, d0.w, d1.x, d1.y, d1.z, d1.w};
#pragma unroll
        for (int k = 0; k < 8; ++k) {
            int b = dd[k] >> BSHIFT;
            uint2 pr = make_uint2((uint)ss[k], (uint)dd[k]);
            int p = atomicAdd(&cnt[b], 1);
            if (p < CAP) buf[b][p] = pr;
            else temp[atomicAdd(&gcur[b], 1)] = pr;
        }
    } else {
        for (int k = 0; k < 8; ++k) {
            if (i0 + k < e) {
                int b = dst[i0 + k] >> BSHIFT;
                uint2 pr = make_uint2((uint)src[i0 + k], (uint)dst[i0 + k]);
                int p = atomicAdd(&cnt[b], 1);
                if (p < CAP) buf[b][p] = pr;
                else temp[atomicAdd(&gcur[b], 1)] = pr;
            }
        }
    }
    __syncthreads();

    c[tid] = min(cnt[tid], CAP);
    sc[tid] = c[tid];
    __syncthreads();
    for (int off = 1; off < 256; off <<= 1) {
        int t = (tid >= off) ? sc[tid - off] : 0;
        __syncthreads();
        sc[tid] += t;
        __syncthreads();
    }
    pre[tid] = sc[tid] - c[tid];
    gb[tid] = (c[tid] > 0) ? atomicAdd(&gcur[tid], c[tid]) : 0;
    if (tid == 0) pre[MAXNB] = sc[MAXNB - 1];
    __syncthreads();

    int S = pre[MAXNB];
    for (int idx = tid; idx < S; idx += 256) {
        int lo = 0, hi = MAXNB;
        while (hi - lo > 1) {
            int mid = (lo + hi) >> 1;
            if (pre[mid] <= idx) lo = mid;
            else hi = mid;
        }
        int ofs = idx - pre[lo];
        temp[gb[lo] + ofs] = buf[lo][ofs];
    }
}

// ---------------- build bucket: 512 nodes/block, wave-shfl scan ----------------
__global__ __launch_bounds__(512) void build_bucket(const uint2* __restrict__ temp,
                                                    const int* __restrict__ bucket_base,
                                                    int* __restrict__ row_start, float* __restrict__ inv_deg,
                                                    int* __restrict__ csr_src, int n) {
    __shared__ int deg[BUCKET], cur[BUCKET], rs[BUCKET], wsum[8];
    int tid = threadIdx.x;
    int b = blockIdx.x;
    int base = bucket_base[b];
    int ecnt = bucket_base[b + 1] - base;
    int node0 = b << BSHIFT;
    int ncnt = min(BUCKET, n - node0);

    deg[tid] = 0;
    __syncthreads();
    for (int i = tid; i < ecnt; i += BUCKET) {
        int d = (int)temp[base + i].y - node0;
        atomicAdd(&deg[d], 1);
    }
    __syncthreads();

    int d = deg[tid];
    int v = d;
#pragma unroll
    for (int off = 1; off < 64; off <<= 1) {
        int t = __shfl_up(v, off);
        if ((tid & 63) >= off) v += t;
    }
    int wv = tid >> 6;  // 0..7
    if ((tid & 63) == 63) wsum[wv] = v;
    __syncthreads();
    if (tid < 8) {
        int w = wsum[tid];
#pragma unroll
        for (int off = 1; off < 8; off <<= 1) {
            int t = __shfl_up(w, off);
            if (tid >= off) w += t;
        }
        wsum[tid] = w;
    }
    __syncthreads();
    int excl = v + (wv ? wsum[wv - 1] : 0) - d;

    if (tid < ncnt) {
        row_start[node0 + tid] = base + excl;
        inv_deg[node0 + tid] = d ? 1.0f / (float)d : 0.0f;
    }
    rs[tid] = excl;
    cur[tid] = 0;
    __syncthreads();
    for (int i = tid; i < ecnt; i += BUCKET) {
        uint2 p = temp[base + i];
        int l = (int)p.y - node0;
        int pos = atomicAdd(&cur[l], 1);
        csr_src[base + rs[l] + pos] = (int)p.x;
    }
}

// ---------------- fused convert: x -> xb [n][128] bf16, weights -> w1cat/w2cat (col-major) ----------------
__global__ __launch_bounds__(256) void convert_all(const float* __restrict__ x, ushort* __restrict__ xb,
                                                   const float* __restrict__ W1s, const float* __restrict__ W1n,
                                                   const float* __restrict__ W2s, const float* __restrict__ W2n,
                                                   ushort* __restrict__ w1cat, ushort* __restrict__ w2cat,
                                                   int total8) {
    int i = blockIdx.x * 256 + threadIdx.x;
    if (i < total8) {
        int e = i * 8;
        float4 v0 = *(const float4*)(x + e);
        float4 v1 = *(const float4*)(x + e + 4);
        uint4 o;
        o.x = pack2(v0.x, v0.y);
        o.y = pack2(v0.z, v0.w);
        o.z = pack2(v1.x, v1.y);
        o.w = pack2(v1.z, v1.w);
        *(uint4*)(xb + e) = o;
    } else {
        int idx = i - total8;
        if (idx < 256 * 128) {
            // w1cat[c][k]: c<128 -> W1n[k][c]; c>=128 -> W1s[k][c-128]
            int c = idx >> 7, k = idx & 127;
            float v = (c < 128) ? W1n[k * 128 + c] : W1s[k * 128 + (c - 128)];
            w1cat[idx] = f2bf(v);
        } else if (idx < 256 * 128 + 128 * 128) {
            int j = idx - 256 * 128;
            int c = j >> 7, k = j & 127;
            float v = (c < 64) ? W2n[k * 64 + c] : W2s[k * 64 + (c - 64)];
            w2cat[j] = f2bf(v);
        }
    }
}

// ---------------- MFMA GEMM: K=128. grid.y=0 -> bf16 out (neigh), y=1 -> f32 out (self) ----------------
// A [n_pad][128] bf16; Wcat [2*NCOL][128] bf16 col-major-of-slice. 4 waves = 2Mx2N.
template <int NTT>
__global__ __launch_bounds__(256) void gemm_mfma(const ushort* __restrict__ A, const ushort* __restrict__ Wcat,
                                                 ushort* __restrict__ Yb, float* __restrict__ Yf, int n) {
    constexpr int NCOL = NTT * 16;
    constexpr int NT = NTT / 2;  // n-tiles per wave
    __shared__ ushort Wlds[NCOL * 128];  // XOR-swizzled rows of 256B

    int tid = threadIdx.x;
    int wave = tid >> 6, lane = tid & 63;
    int wm = wave >> 1, wn = wave & 1;
    int lrow = lane & 15, lk = lane >> 4;
    int m0 = blockIdx.x * 128 + wm * 64;
    const ushort* W = Wcat + (size_t)blockIdx.y * NCOL * 128;

    // stage W slice: NCOL rows x 128 k
    for (int f = tid; f < NCOL * 16; f += 256) {
        int c = f >> 4;
        int kk = (f & 15) * 8;
        uint4 w = *(const uint4*)(W + c * 128 + kk);
        uint baddr = ((uint)(c * 256 + kk * 2)) ^ ((uint)(c & 7) << 4);
        *(uint4*)((char*)Wlds + baddr) = w;
    }
    // A fragments (issue before barrier)
    bf16x8 af[4][4];
#pragma unroll
    for (int mi = 0; mi < 4; ++mi) {
        const ushort* Ar = A + (size_t)(m0 + mi * 16 + lrow) * 128 + lk * 8;
#pragma unroll
        for (int ks = 0; ks < 4; ++ks) af[mi][ks] = *(const bf16x8*)(Ar + ks * 32);
    }

    f32x4 acc[4][NT];
#pragma unroll
    for (int mi = 0; mi < 4; ++mi)
#pragma unroll
        for (int nj = 0; nj < NT; ++nj) acc[mi][nj] = (f32x4)0.f;

    __syncthreads();

#pragma unroll
    for (int ks = 0; ks < 4; ++ks) {
#pragma unroll
        for (int nj = 0; nj < NT; ++nj) {
            int c = (wn * NT + nj) * 16 + lrow;
            uint baddr = ((uint)(c * 256 + (ks * 32 + lk * 8) * 2)) ^ ((uint)(c & 7) << 4);
            bf16x8 b = *(const bf16x8*)((const char*)Wlds + baddr);
#pragma unroll
            for (int mi = 0; mi < 4; ++mi)
                acc[mi][nj] = __builtin_amdgcn_mfma_f32_16x16x32_bf16(af[mi][ks], b, acc[mi][nj], 0, 0, 0);
        }
    }

    // epilogue: C/D layout col=lane&15, row=(lane>>4)*4+r  [m89]
    bool selfhalf = (blockIdx.y != 0);
#pragma unroll
    for (int nj = 0; nj < NT; ++nj) {
        int col = (wn * NT + nj) * 16 + lrow;
#pragma unroll
        for (int mi = 0; mi < 4; ++mi) {
#pragma unroll
            for (int r = 0; r < 4; ++r) {
                int row = m0 + mi * 16 + lk * 4 + r;
                if (row >= n) continue;
                float v = acc[mi][nj][r];
                if (selfhalf)
                    Yf[(size_t)row * NCOL + col] = v;
                else
                    Yb[(size_t)row * NCOL + col] = f2bf(v);
            }
        }
    }
}

// ---------------- agg1: 16 lanes/node, gather Pn (256B rows), fuse self+bias+relu -> h bf16 ----------------
__global__ __launch_bounds__(256) void agg_layer1(const ushort* __restrict__ Pn, const float* __restrict__ Ps,
                                                  const int* __restrict__ row_start, const int* __restrict__ csr_src,
                                                  const float* __restrict__ inv_deg, const float* __restrict__ bias,
                                                  ushort* __restrict__ hb, int n) {
    int g = (blockIdx.x * 256 + threadIdx.x) >> 4;
    int ngroups = gridDim.x * 16;
    int gl = threadIdx.x & 15;
    const uint4* fb = (const uint4*)Pn;  // 16 uint4 per 256B row

    for (int node = g; node < n; node += ngroups) {
        int beg = row_start[node];
        int end = row_start[node + 1];

        float a[8];
#pragma unroll
        for (int j = 0; j < 8; ++j) a[j] = 0.f;

        int ei = beg;
        for (; ei + 4 <= end; ei += 4) {
            int s0 = csr_src[ei];
            int s1 = csr_src[ei + 1];
            int s2 = csr_src[ei + 2];
            int s3 = csr_src[ei + 3];
            uint4 v0 = fb[(size_t)s0 * 16 + gl];
            uint4 v1 = fb[(size_t)s1 * 16 + gl];
            uint4 v2 = fb[(size_t)s2 * 16 + gl];
            uint4 v3 = fb[(size_t)s3 * 16 + gl];
            acc8(a, v0);
            acc8(a, v1);
            acc8(a, v2);
            acc8(a, v3);
        }
        for (; ei < end; ++ei) {
            int s = csr_src[ei];
            uint4 v = fb[(size_t)s * 16 + gl];
            acc8(a, v);
        }

        float w = inv_deg[node];
        float4 s0 = *(const float4*)(Ps + (size_t)node * 128 + gl * 8);
        float4 s1 = *(const float4*)(Ps + (size_t)node * 128 + gl * 8 + 4);
        float4 b0 = *(const float4*)(bias + gl * 8);
        float4 b1 = *(const float4*)(bias + gl * 8 + 4);
        float o[8];
        o[0] = fmaxf(a[0] * w + s0.x + b0.x, 0.f);
        o[1] = fmaxf(a[1] * w + s0.y + b0.y, 0.f);
        o[2] = fmaxf(a[2] * w + s0.z + b0.z, 0.f);
        o[3] = fmaxf(a[3] * w + s0.w + b0.w, 0.f);
        o[4] = fmaxf(a[4] * w + s1.x + b1.x, 0.f);
        o[5] = fmaxf(a[5] * w + s1.y + b1.y, 0.f);
        o[6] = fmaxf(a[6] * w + s1.z + b1.z, 0.f);
        o[7] = fmaxf(a[7] * w + s1.w + b1.w, 0.f);
        uint4 ov;
        ov.x = pack2(o[0], o[1]);
        ov.y = pack2(o[2], o[3]);
        ov.z = pack2(o[4], o[5]);
        ov.w = pack2(o[6], o[7]);
        *(uint4*)(hb + (size_t)node * 128 + gl * 8) = ov;
    }
}

// ---------------- agg2: 8 lanes/node, gather Tn (128B rows), fuse self+bias -> out f32 ----------------
__global__ __launch_bounds__(256) void agg_layer2(const ushort* __restrict__ Tn, const float* __restrict__ Ts,
                                                  const int* __restrict__ row_start, const int* __restrict__ csr_src,
                                                  const float* __restrict__ inv_deg, const float* __restrict__ bias,
                                                  float* __restrict__ out, int n) {
    int g = (blockIdx.x * 256 + threadIdx.x) >> 3;
    int ngroups = gridDim.x * 32;
    int gl = threadIdx.x & 7;
    const uint4* fb = (const uint4*)Tn;  // 8 uint4 per 128B row

    for (int node = g; node < n; node += ngroups) {
        int beg = row_start[node];
        int end = row_start[node + 1];

        float a[8];
#pragma unroll
        for (int j = 0; j < 8; ++j) a[j] = 0.f;

        int ei = beg;
        for (; ei + 4 <= end; ei += 4) {
            int s0 = csr_src[ei];
            int s1 = csr_src[ei + 1];
            int s2 = csr_src[ei + 2];
            int s3 = csr_src[ei + 3];
            uint4 v0 = fb[(size_t)s0 * 8 + gl];
            uint4 v1 = fb[(size_t)s1 * 8 + gl];
            uint4 v2 = fb[(size_t)s2 * 8 + gl];
            uint4 v3 = fb[(size_t)s3 * 8 + gl];
            acc8(a, v0);
            acc8(a, v1);
            acc8(a, v2);
            acc8(a, v3);
        }
        for (; ei < end; ++ei) {
            int s = csr_src[ei];
            uint4 v = fb[(size_t)s * 8 + gl];
            acc8(a, v);
        }

        float w = inv_deg[node];
        float4 s0 = *(const float4*)(Ts + (size_t)node * 64 + gl * 8);
        float4 s1 = *(const float4*)(Ts + (size_t)node * 64 + gl * 8 + 4);
        float4 b0 = *(const float4*)(bias + gl * 8);
        float4 b1 = *(const float4*)(bias + gl * 8 + 4);
        float4 o0, o1;
        o0.x = a[0] * w + s0.x + b0.x;
        o0.y = a[1] * w + s0.y + b0.y;
        o0.z = a[2] * w + s0.z + b0.z;
        o0.w = a[3] * w + s0.w + b0.w;
        o1.x = a[4] * w + s1.x + b1.x;
        o1.y = a[5] * w + s1.y + b1.y;
        o1.z = a[6] * w + s1.z + b1.z;
        o1.w = a[7] * w + s1.w + b1.w;
        *(float4*)(out + (size_t)node * 64 + gl * 8) = o0;
        *(float4*)(out + (size_t)node * 64 + gl * 8 + 4) = o1;
    }
}

extern "C" void kernel_launch(void* const* d_in, const int* in_sizes, int n_in,
                              void* d_out, int out_size, void* d_ws, size_t ws_size,
                              hipStream_t stream) {
    const float* x   = (const float*)d_in[0];
    const int*   src = (const int*)d_in[1];
    const int*   dst = (const int*)d_in[2];
    const float* W1s = (const float*)d_in[3];
    const float* W1n = (const float*)d_in[4];
    const float* b1  = (const float*)d_in[5];
    const float* W2s = (const float*)d_in[6];
    const float* W2n = (const float*)d_in[7];
    const float* b2  = (const float*)d_in[8];
    float* out = (float*)d_out;

    const int n = in_sizes[0] / D_FEAT;         // 100000
    const int e = in_sizes[1];                  // 1600000
    const int nb = (n + BUCKET - 1) >> BSHIFT;  // 196
    const int n_pad = (n + 127) & ~127;

    // ---- workspace carve ----
    char* ws = (char*)d_ws;
    auto take = [&](size_t bytes) {
        void* p = (void*)ws;
        ws += (bytes + 255) & ~(size_t)255;
        return p;
    };
    int*    bucket_cnt  = (int*)take((size_t)MAXNB * 4);
    int*    bucket_base = (int*)take((size_t)(MAXNB + 1) * 4);
    int*    gcur        = (int*)take((size_t)MAXNB * 4);
    int*    row_start   = (int*)take((size_t)(n + 1) * 4);
    float*  inv_deg     = (float*)take((size_t)n * 4);
    int*    csr_src     = (int*)take((size_t)e * 4);
    ushort* xb          = (ushort*)take((size_t)n_pad * 128 * 2);
    ushort* Pn          = (ushort*)take((size_t)n_pad * 128 * 2);
    float*  Ps          = (float*)take((size_t)n_pad * 128 * 4);  // also reused for Tn+Ts
    ushort* hb          = (ushort*)take((size_t)n_pad * 128 * 2);
    ushort* w1cat       = (ushort*)take((size_t)256 * 128 * 2);
    ushort* w2cat       = (ushort*)take((size_t)128 * 128 * 2);
    uint2*  temp        = (uint2*)hb;             // alias: dead until agg1 writes hb
    ushort* Tn          = (ushort*)Ps;            // alias: Ps dead after agg1
    float*  Ts          = (float*)((char*)Ps + (size_t)n_pad * 64 * 2);

    hipMemsetAsync(bucket_cnt, 0, MAXNB * 4, stream);

    const int ebk = (e + 2047) / 2048;
    bucket_hist<<<ebk, 256, 0, stream>>>(dst, bucket_cnt, e, nb);

    const int total8 = n * 16;
    const int cvt_items = total8 + 256 * 128 + 128 * 128;
    convert_all<<<(cvt_items + 255) / 256, 256, 0, stream>>>(x, xb, W1s, W1n, W2s, W2n, w1cat, w2cat, total8);

    bucket_scan<<<1, 256, 0, stream>>>(bucket_cnt, bucket_base, gcur, row_start, nb, n, e);
    bin_edges<<<ebk, 256, 0, stream>>>(src, dst, gcur, temp, e);
    build_bucket<<<nb, BUCKET, 0, stream>>>(temp, bucket_base, row_start, inv_deg, csr_src, n);

    // layer 1: Pn = x@W1n (bf16), Ps = x@W1s (f32); h = relu(Ps + mean(Pn) + b1)
    gemm_mfma<8><<<dim3(n_pad / 128, 2), 256, 0, stream>>>(xb, w1cat, Pn, Ps, n);
    agg_layer1<<<3125, 256, 0, stream>>>(Pn, Ps, row_start, csr_src, inv_deg, b1, hb, n);

    // layer 2: Tn = h@W2n (bf16), Ts = h@W2s (f32); out = Ts + mean(Tn) + b2
    gemm_mfma<4><<<dim3(n_pad / 128, 2), 256, 0, stream>>>(hb, w2cat, Tn, Ts, n);
    agg_layer2<<<3125, 256, 0, stream>>>(Tn, Ts, row_start, csr_src, inv_deg, b2, out, n);
}